// Round 1
// baseline (1948.608 us; speedup 1.0000x reference)
//
#include <hip/hip_runtime.h>
#include <hip/hip_bf16.h>
#include <cstdint>
#include <cstddef>

// Problem: out[t,o] = sum_d x[t,d] * (qw[o,d]*scale) + qbias[o]*bias_scale
//   x:  [8192, 4096]  fp32
//   qw: [16384, 4096] int32 (int8-valued, exact in bf16)
//   out:[8192, 16384] fp32
// Strategy: convert x->bf16 (rounding), qw->bf16 (exact, unscaled),
// m97-style 128x128x32 bf16 MFMA GEMM with global_load_lds(16B) staging,
// apply scale & bias in epilogue.  Fallback (small ws): fused-conversion GEMM.

typedef __bf16 v8bf  __attribute__((ext_vector_type(8)));
typedef float  f32x4 __attribute__((ext_vector_type(4)));

constexpr int M = 8192;
constexpr int N = 16384;
constexpr int K = 4096;
constexpr int BM = 128, BN = 128, BK = 32;

__device__ __forceinline__ unsigned f2bf(float f) {
  union { float f; unsigned u; } v; v.f = f;
  // round-to-nearest-even on the raw bits (inputs are finite)
  return (v.u + 0x7fffu + ((v.u >> 16) & 1u)) >> 16;
}

// ---------------- conversion kernels (fast path) ----------------

__global__ __launch_bounds__(256) void cvt_x_bf16(const float4* __restrict__ in,
                                                  uint2* __restrict__ out) {
  size_t i = (size_t)blockIdx.x * 256 + threadIdx.x;
  float4 a = in[i];
  uint2 o;
  o.x = f2bf(a.x) | (f2bf(a.y) << 16);
  o.y = f2bf(a.z) | (f2bf(a.w) << 16);
  out[i] = o;
}

__global__ __launch_bounds__(256) void cvt_w_bf16(const int4* __restrict__ in,
                                                  uint2* __restrict__ out) {
  size_t i = (size_t)blockIdx.x * 256 + threadIdx.x;
  int4 a = in[i];
  uint2 o;
  o.x = f2bf((float)a.x) | (f2bf((float)a.y) << 16);   // exact for |v|<=127
  o.y = f2bf((float)a.z) | (f2bf((float)a.w) << 16);
  out[i] = o;
}

// ---------------- fast GEMM: bf16 A [M,K], bf16 B^T [N,K] ----------------

__global__ __launch_bounds__(256) void gemm_bt(const __bf16* __restrict__ A,
                                               const __bf16* __restrict__ B,
                                               const int* __restrict__ qbias,
                                               const float* __restrict__ scale,
                                               const float* __restrict__ bscale,
                                               float* __restrict__ C) {
  __shared__ __bf16 As[BM * BK];   // row-major, K contiguous, UNPADDED (global_load_lds)
  __shared__ __bf16 Bs[BN * BK];

  const int t    = threadIdx.x;
  const int wave = t >> 6;
  const int lane = t & 63;
  const int quad = lane >> 4;
  const int l16  = lane & 15;
  const int m0   = blockIdx.y * BM;
  const int n0   = blockIdx.x * BN;
  const int wm   = (wave & 1) * 64;   // wave's 64x64 sub-tile
  const int wn   = (wave >> 1) * 64;

  // staging: thread t -> row t>>2 (and +64), 16B segment (t&3)*8 elems
  const int srow = t >> 2;
  const int scol = (t & 3) * 8;
  const __bf16* gA = A + (size_t)(m0 + srow) * K + scol;
  const __bf16* gB = B + (size_t)(n0 + srow) * K + scol;
  // wave-uniform LDS bases: wave w covers rows [16w,16w+16) => byte w*1024
  __bf16* lA = As + wave * 512;
  __bf16* lB = Bs + wave * 512;

  f32x4 acc[4][4] = {};

  for (int k0 = 0; k0 < K; k0 += BK) {
    __syncthreads();   // previous tile fully consumed
    __builtin_amdgcn_global_load_lds((const __attribute__((address_space(1))) void*)gA,
                                     (__attribute__((address_space(3))) void*)lA, 16, 0, 0);
    __builtin_amdgcn_global_load_lds((const __attribute__((address_space(1))) void*)(gA + (size_t)64 * K),
                                     (__attribute__((address_space(3))) void*)(lA + 2048), 16, 0, 0);
    __builtin_amdgcn_global_load_lds((const __attribute__((address_space(1))) void*)gB,
                                     (__attribute__((address_space(3))) void*)lB, 16, 0, 0);
    __builtin_amdgcn_global_load_lds((const __attribute__((address_space(1))) void*)(gB + (size_t)64 * K),
                                     (__attribute__((address_space(3))) void*)(lB + 2048), 16, 0, 0);
    gA += BK; gB += BK;
    __syncthreads();   // drains vmcnt(0): staging complete

    v8bf a[4], b[4];
#pragma unroll
    for (int i = 0; i < 4; ++i) {
      a[i] = *(const v8bf*)(As + (wm + i * 16 + l16) * BK + quad * 8);
      b[i] = *(const v8bf*)(Bs + (wn + i * 16 + l16) * BK + quad * 8);
    }
#pragma unroll
    for (int im = 0; im < 4; ++im)
#pragma unroll
      for (int in = 0; in < 4; ++in)
        acc[im][in] = __builtin_amdgcn_mfma_f32_16x16x32_bf16(a[im], b[in], acc[im][in], 0, 0, 0);
  }

  const float s  = scale[0];
  const float bs = bscale[0];
#pragma unroll
  for (int in = 0; in < 4; ++in) {
    const int col = n0 + wn + in * 16 + l16;
    const float bias = (float)qbias[col] * bs;
#pragma unroll
    for (int im = 0; im < 4; ++im) {
      const int row = m0 + wm + im * 16 + quad * 4;   // + r
      float* cp = C + (size_t)row * N + col;
#pragma unroll
      for (int r = 0; r < 4; ++r)
        cp[(size_t)r * N] = acc[im][in][r] * s + bias;
    }
  }
}

// ---------------- fallback: fused-conversion GEMM (no workspace) ----------------

__device__ __forceinline__ uint4 packf(float4 x, float4 y) {
  uint4 o;
  o.x = f2bf(x.x) | (f2bf(x.y) << 16);
  o.y = f2bf(x.z) | (f2bf(x.w) << 16);
  o.z = f2bf(y.x) | (f2bf(y.y) << 16);
  o.w = f2bf(y.z) | (f2bf(y.w) << 16);
  return o;
}
__device__ __forceinline__ uint4 packi(int4 x, int4 y) {
  uint4 o;
  o.x = f2bf((float)x.x) | (f2bf((float)x.y) << 16);
  o.y = f2bf((float)x.z) | (f2bf((float)x.w) << 16);
  o.z = f2bf((float)y.x) | (f2bf((float)y.y) << 16);
  o.w = f2bf((float)y.z) | (f2bf((float)y.w) << 16);
  return o;
}

__global__ __launch_bounds__(256) void gemm_fused(const float* __restrict__ A32,
                                                  const int* __restrict__ W32,
                                                  const int* __restrict__ qbias,
                                                  const float* __restrict__ scale,
                                                  const float* __restrict__ bscale,
                                                  float* __restrict__ C) {
  __shared__ __bf16 As[BM * BK];
  __shared__ __bf16 Bs[BN * BK];

  const int t    = threadIdx.x;
  const int wave = t >> 6;
  const int lane = t & 63;
  const int quad = lane >> 4;
  const int l16  = lane & 15;
  const int m0   = blockIdx.y * BM;
  const int n0   = blockIdx.x * BN;
  const int wm   = (wave & 1) * 64;
  const int wn   = (wave >> 1) * 64;

  // staging: thread t -> row t>>1, half (t&1)*16 elems
  const int srow = t >> 1;
  const int sh   = (t & 1) * 16;
  const float* gA = A32 + (size_t)(m0 + srow) * K + sh;
  const int*   gW = W32 + (size_t)(n0 + srow) * K + sh;
  __bf16* wA = As + srow * BK + sh;
  __bf16* wB = Bs + srow * BK + sh;

  f32x4 acc[4][4] = {};

  for (int k0 = 0; k0 < K; k0 += BK) {
    float4 a0 = *(const float4*)(gA + 0);
    float4 a1 = *(const float4*)(gA + 4);
    float4 a2 = *(const float4*)(gA + 8);
    float4 a3 = *(const float4*)(gA + 12);
    int4 b0 = *(const int4*)(gW + 0);
    int4 b1 = *(const int4*)(gW + 4);
    int4 b2 = *(const int4*)(gW + 8);
    int4 b3 = *(const int4*)(gW + 12);
    gA += BK; gW += BK;
    __syncthreads();   // previous tile fully consumed
    ((uint4*)wA)[0] = packf(a0, a1);
    ((uint4*)wA)[1] = packf(a2, a3);
    ((uint4*)wB)[0] = packi(b0, b1);
    ((uint4*)wB)[1] = packi(b2, b3);
    __syncthreads();

    v8bf a[4], b[4];
#pragma unroll
    for (int i = 0; i < 4; ++i) {
      a[i] = *(const v8bf*)(As + (wm + i * 16 + l16) * BK + quad * 8);
      b[i] = *(const v8bf*)(Bs + (wn + i * 16 + l16) * BK + quad * 8);
    }
#pragma unroll
    for (int im = 0; im < 4; ++im)
#pragma unroll
      for (int in = 0; in < 4; ++in)
        acc[im][in] = __builtin_amdgcn_mfma_f32_16x16x32_bf16(a[im], b[in], acc[im][in], 0, 0, 0);
  }

  const float s  = scale[0];
  const float bs = bscale[0];
#pragma unroll
  for (int in = 0; in < 4; ++in) {
    const int col = n0 + wn + in * 16 + l16;
    const float bias = (float)qbias[col] * bs;
#pragma unroll
    for (int im = 0; im < 4; ++im) {
      const int row = m0 + wm + im * 16 + quad * 4;
      float* cp = C + (size_t)row * N + col;
#pragma unroll
      for (int r = 0; r < 4; ++r)
        cp[(size_t)r * N] = acc[im][in][r] * s + bias;
    }
  }
}

extern "C" void kernel_launch(void* const* d_in, const int* in_sizes, int n_in,
                              void* d_out, int out_size, void* d_ws, size_t ws_size,
                              hipStream_t stream) {
  const float* x      = (const float*)d_in[0];   // [M,K] fp32
  const int*   qw     = (const int*)d_in[1];     // [N,K] int32
  const int*   qbias  = (const int*)d_in[2];     // [N]
  const float* scale  = (const float*)d_in[3];
  const float* bscale = (const float*)d_in[4];
  float* out = (float*)d_out;                    // [M,N] fp32

  const size_t needA = (size_t)M * K * sizeof(__bf16);   //  64 MiB
  const size_t needB = (size_t)N * K * sizeof(__bf16);   // 128 MiB
  dim3 grid(N / BN, M / BM);                              // (128, 64)

  if (ws_size >= needA + needB) {
    __bf16* wsA = (__bf16*)d_ws;
    __bf16* wsB = wsA + (size_t)M * K;
    cvt_x_bf16<<<(int)((size_t)M * K / (4 * 256)), 256, 0, stream>>>(
        (const float4*)x, (uint2*)wsA);
    cvt_w_bf16<<<(int)((size_t)N * K / (4 * 256)), 256, 0, stream>>>(
        (const int4*)qw, (uint2*)wsB);
    gemm_bt<<<grid, 256, 0, stream>>>(wsA, wsB, qbias, scale, bscale, out);
  } else {
    gemm_fused<<<grid, 256, 0, stream>>>(x, qw, qbias, scale, bscale, out);
  }
}